// Round 8
// baseline (1557.146 us; speedup 1.0000x reference)
//
#include <hip/hip_runtime.h>
#include <math.h>

#define CH 64
#define HH 128
#define WW 128
#define HW 16384
#define NVALS 131072.f

// ws layout (floats):
//  weff2: ((g*64+c)*9+k)*27 + j   62208 floats
//  bias2: g*27 + j                  108 floats
//  wT:    g*36864 + c*576 + k*64+o 147456 floats
//  stats: sum[64] sumsq[64] a[64] b[64]  256 floats
//  oacc:  ((b*4+g)*27+j)*16384+px  3538944 floats
#define WEFF2 0
#define BIAS2 62208
#define WTOFF 62464
#define STATS 209920
#define OACC  210176

__device__ __forceinline__ int off_chan(int g, int j) {
    return (j < 18) ? (g * 18 + j) : (72 + g * 9 + (j - 18));
}

__global__ void prep(const float* __restrict__ w_offset, const float* __restrict__ b_offset,
                     const float* __restrict__ w_dcn, float* __restrict__ ws) {
    int tid = blockIdx.x * 256 + threadIdx.x;
    if (tid < 147456) {
        int o = tid & 63;
        int k = (tid >> 6) % 9;
        int c = (tid / 576) & 63;
        int g = tid / 36864;
        ws[WTOFF + tid] = w_dcn[((g * 64 + o) * 64 + c) * 9 + k];
    }
    if (tid < 62208) {
        int j = tid % 27;
        int r = tid / 27;
        int k = r % 9;
        int gc = r / 9;
        int c = gc & 63;
        int g = gc >> 6;
        int o = off_chan(g, j);
        float s = 0.f;
#pragma unroll
        for (int ss = 0; ss < 4; ++ss)
            s += w_offset[(o * 256 + ss * 64 + c) * 9 + k];
        ws[WEFF2 + tid] = s;
    }
    if (tid < 108) {
        int g = tid / 27, j = tid % 27;
        ws[BIAS2 + tid] = b_offset[off_chan(g, j)];
    }
    if (tid < 128) ws[STATS + tid] = 0.f;
}

// offset conv.  flat grid 512.  XCD owns (b, row-quarter): xcd = blk&7.
// unit = blk>>3 (0..63): tl = unit&15 (local tile), g = unit>>4
template <int JBASE, int JN>
__global__ __launch_bounds__(256, 2) void conv_off(const float* __restrict__ x,
                                                   float* __restrict__ ws) {
    int blk = blockIdx.x;
    int xcd = blk & 7;
    int b = xcd >> 2;
    int quad = xcd & 3;
    int unit = blk >> 3;
    int tl = unit & 15;
    int g = unit >> 4;
    int th = quad * 2 + (tl >> 3);
    int tw = tl & 7;
    int t = threadIdx.x;
    int h = th * 16 + (t >> 4);
    int w = tw * 16 + (t & 15);
    const float* xb = x + b * CH * HW;

    float oacc[JN];
    const float* bp = ws + BIAS2 + g * 27 + JBASE;
#pragma unroll
    for (int j = 0; j < JN; ++j) oacc[j] = bp[j];

    int offs[9];
    float vmask[9];
#pragma unroll
    for (int k = 0; k < 9; ++k) {
        int yy = h + k / 3 - 1, xx = w + k % 3 - 1;
        bool v = (yy >= 0) && (yy < HH) && (xx >= 0) && (xx < WW);
        vmask[k] = v ? 1.f : 0.f;
        offs[k] = min(max(yy, 0), HH - 1) * WW + min(max(xx, 0), WW - 1);
    }

    const float* wp0 = ws + WEFF2 + (g * 64) * 243 + JBASE;

    // two-stage pipeline over c-pairs: 18 loads in flight ahead of FMAs
    float xra[2][9], xrb[2][9];
#define CLOAD(dst, c0_)                                            \
    {                                                              \
        _Pragma("unroll") for (int cc = 0; cc < 2; ++cc) {         \
            const float* xp = xb + ((c0_) + cc) * HW;              \
            _Pragma("unroll") for (int k = 0; k < 9; ++k)          \
                dst[cc][k] = xp[offs[k]];                          \
        }                                                          \
    }
#define CFMA(src, c0_)                                             \
    {                                                              \
        _Pragma("unroll") for (int cc = 0; cc < 2; ++cc) {         \
            const float* wp = wp0 + ((c0_) + cc) * 243;            \
            _Pragma("unroll") for (int k = 0; k < 9; ++k) {        \
                float xv = src[cc][k] * vmask[k];                  \
                _Pragma("unroll") for (int j = 0; j < JN; ++j)     \
                    oacc[j] = fmaf(xv, wp[k * 27 + j], oacc[j]);   \
            }                                                      \
        }                                                          \
    }
    CLOAD(xra, 0);
#pragma unroll
    for (int c0 = 0; c0 < CH; c0 += 4) {
        CLOAD(xrb, c0 + 2);
        CFMA(xra, c0);
        if (c0 + 4 < CH) CLOAD(xra, c0 + 4);
        CFMA(xrb, c0 + 2);
    }
#undef CLOAD
#undef CFMA

    float* op = ws + OACC + (size_t)((b * 4 + g) * 27 + JBASE) * HW + h * WW + w;
#pragma unroll
    for (int j = 0; j < JN; ++j) op[(size_t)j * HW] = oacc[j];
}

// deformable conv, o-chunked (32/block).  flat grid 1024.
// xcd = blk&7 -> (b = xcd>>2, quad = xcd&3).  unit = blk>>3 (0..127):
// tl = unit&15 (tile within quarter), go = unit>>4: g = go&3, ohalf = go>>2
__global__ __launch_bounds__(256, 2) void dcn(const float* __restrict__ x,
                                              const float* __restrict__ ws,
                                              float* __restrict__ out,
                                              float* __restrict__ stats) {
    int blk = blockIdx.x;
    int xcd = blk & 7;
    int b = xcd >> 2;
    int quad = xcd & 3;
    int unit = blk >> 3;
    int tl = unit & 15;
    int go = unit >> 4;
    int g = go & 3;
    int obase = (go >> 2) * 32;
    int th = quad * 2 + (tl >> 3);
    int tw = tl & 7;
    int t = threadIdx.x;
    int h = th * 16 + (t >> 4);
    int w = tw * 16 + (t & 15);
    int px = h * WW + w;
    const float* xb = x + b * CH * HW;
    const float* ob_in = ws + OACC + (size_t)(b * 4 + g) * 27 * HW + px;

    float acc[32];
#pragma unroll
    for (int o = 0; o < 32; ++o) acc[o] = 0.f;

    const float* wg = ws + WTOFF + g * 36864 + obase;
#pragma unroll
    for (int k = 0; k < 9; ++k) {
        float dy = ob_in[(size_t)(2 * k) * HW];
        float dx = ob_in[(size_t)(2 * k + 1) * HW];
        float mk = 1.f / (1.f + expf(-ob_in[(size_t)(18 + k) * HW]));

        float py = (float)h + (float)(k / 3 - 1) + dy;
        float qx = (float)w + (float)(k % 3 - 1) + dx;
        float y0f = floorf(py), x0f = floorf(qx);
        float ly = py - y0f, lx = qx - x0f;
        int y0 = (int)y0f, x0 = (int)x0f;
        int y1 = y0 + 1, x1 = x0 + 1;

        bool vy0 = (y0 >= 0) && (y0 < HH), vy1 = (y1 >= 0) && (y1 < HH);
        bool vx0 = (x0 >= 0) && (x0 < WW), vx1 = (x1 >= 0) && (x1 < WW);
        int yc0 = min(max(y0, 0), HH - 1), yc1 = min(max(y1, 0), HH - 1);
        int xc0 = min(max(x0, 0), WW - 1), xc1 = min(max(x1, 0), WW - 1);
        int i00 = yc0 * WW + xc0, i01 = yc0 * WW + xc1;
        int i10 = yc1 * WW + xc0, i11 = yc1 * WW + xc1;

        float w00 = (1.f - ly) * (1.f - lx) * mk * ((vy0 && vx0) ? 1.f : 0.f);
        float w01 = (1.f - ly) * lx * mk * ((vy0 && vx1) ? 1.f : 0.f);
        float w10 = ly * (1.f - lx) * mk * ((vy1 && vx0) ? 1.f : 0.f);
        float w11 = ly * lx * mk * ((vy1 && vx1) ? 1.f : 0.f);

        const float* wk = wg + k * 64;

        // two-stage pipeline over 8-channel groups: 32 gathers in flight
        float xa[8][4], xb_[8][4];
#define LOAD8(dst, c0_)                                            \
    {                                                              \
        _Pragma("unroll") for (int cc = 0; cc < 8; ++cc) {         \
            const float* xp = xb + ((c0_) + cc) * HW;              \
            dst[cc][0] = xp[i00];                                  \
            dst[cc][1] = xp[i01];                                  \
            dst[cc][2] = xp[i10];                                  \
            dst[cc][3] = xp[i11];                                  \
        }                                                          \
    }
#define FMA8(src, c0_)                                             \
    {                                                              \
        _Pragma("unroll") for (int cc = 0; cc < 8; ++cc) {         \
            float col = w00 * src[cc][0] + w01 * src[cc][1]        \
                      + w10 * src[cc][2] + w11 * src[cc][3];       \
            const float* wp = wk + ((c0_) + cc) * 576;             \
            _Pragma("unroll") for (int o = 0; o < 32; ++o)         \
                acc[o] = fmaf(col, wp[o], acc[o]);                 \
        }                                                          \
    }
        LOAD8(xa, 0);
#pragma unroll
        for (int c0 = 0; c0 < CH; c0 += 16) {
            LOAD8(xb_, c0 + 8);
            FMA8(xa, c0);
            if (c0 + 16 < CH) LOAD8(xa, c0 + 16);
            FMA8(xb_, c0 + 8);
        }
#undef LOAD8
#undef FMA8
    }

    int h2 = h * 2 + (g >> 1), w2 = w * 2 + (g & 1);
    float* op = out + (size_t)b * 64 * 65536 + (size_t)obase * 65536
              + (size_t)h2 * 256 + w2;
#pragma unroll
    for (int o = 0; o < 32; ++o)
        op[(size_t)o * 65536] = acc[o];

#pragma unroll
    for (int o = 0; o < 32; ++o) {
        float v = acc[o];
        float v2 = v * v;
#pragma unroll
        for (int m = 32; m >= 1; m >>= 1) {
            v += __shfl_xor(v, m);
            v2 += __shfl_xor(v2, m);
        }
        if ((t & 63) == 0) {
            atomicAdd(stats + obase + o, v);
            atomicAdd(stats + 64 + obase + o, v2);
        }
    }
}

__global__ void finalize(const float* __restrict__ stats,
                         const float* __restrict__ gamma,
                         const float* __restrict__ beta,
                         float* __restrict__ ab) {
    int t = threadIdx.x;
    if (t < 64) {
        float mean = stats[t] / NVALS;
        float var = stats[64 + t] / NVALS - mean * mean;
        var = fmaxf(var, 0.f);
        float a = gamma[t] * rsqrtf(var + 1e-5f);
        ab[t] = a;
        ab[64 + t] = beta[t] - mean * a;
    }
}

__global__ void norm_relu(float* __restrict__ out, const float* __restrict__ ab) {
    size_t tid = (size_t)blockIdx.x * 256 + threadIdx.x;
    size_t base = tid * 4;
    int o = (int)((base >> 16) & 63);
    float a = ab[o], bb = ab[64 + o];
    float4* p = (float4*)(out + base);
    float4 v = *p;
    v.x = fmaxf(fmaf(v.x, a, bb), 0.f);
    v.y = fmaxf(fmaf(v.y, a, bb), 0.f);
    v.z = fmaxf(fmaf(v.z, a, bb), 0.f);
    v.w = fmaxf(fmaf(v.w, a, bb), 0.f);
    *p = v;
}

extern "C" void kernel_launch(void* const* d_in, const int* in_sizes, int n_in,
                              void* d_out, int out_size, void* d_ws, size_t ws_size,
                              hipStream_t stream) {
    const float* x        = (const float*)d_in[0];
    const float* w_offset = (const float*)d_in[1];
    const float* b_offset = (const float*)d_in[2];
    const float* w_dcn    = (const float*)d_in[3];
    const float* gamma    = (const float*)d_in[4];
    const float* beta     = (const float*)d_in[5];
    float* out            = (float*)d_out;
    float* ws = (float*)d_ws;

    prep<<<576, 256, 0, stream>>>(w_offset, b_offset, w_dcn, ws);
    conv_off<0, 14><<<512, 256, 0, stream>>>(x, ws);
    conv_off<14, 13><<<512, 256, 0, stream>>>(x, ws);
    dcn<<<1024, 256, 0, stream>>>(x, ws, out, ws + STATS);
    finalize<<<1, 64, 0, stream>>>(ws + STATS, gamma, beta, ws + STATS + 128);
    norm_relu<<<8192, 256, 0, stream>>>(out, ws + STATS + 128);
}

// Round 9
// 1463.990 us; speedup vs baseline: 1.0636x; 1.0636x over previous
//
#include <hip/hip_runtime.h>
#include <hip/hip_bf16.h>
#include <math.h>

#define CH 64
#define HH 128
#define WW 128
#define HW 16384
#define NVALS 131072.f

// ws layout (float offsets):
//  WEFF2 62208 f | BIAS2 108 f | WTOFF 147456 f | STATS 256 f
//  OACC: ushort region, 3538944 bf16 (offset-conv out, [b][g][j][px])
//  XT:   ushort region, 2097152 bf16 (x transposed, [b][px][c])
// total 12.1 MB (< 15 MB empirically established)
#define WEFF2 0
#define BIAS2 62208
#define WTOFF 62464
#define STATS 209920
#define OACC  210176
#define XT    1979648

typedef unsigned short ushort_t;
typedef unsigned int uint_t;

__device__ __forceinline__ float bflo(uint_t u) { return __uint_as_float(u << 16); }
__device__ __forceinline__ float bfhi(uint_t u) { return __uint_as_float(u & 0xFFFF0000u); }
__device__ __forceinline__ float bfu(ushort_t s) { return __uint_as_float(((uint_t)s) << 16); }
__device__ __forceinline__ ushort_t f2bf(float f) {
    __hip_bfloat16 h = __float2bfloat16(f);
    return *(ushort_t*)&h;
}

__device__ __forceinline__ int off_chan(int g, int j) {
    return (j < 18) ? (g * 18 + j) : (72 + g * 9 + (j - 18));
}

__global__ void prep(const float* __restrict__ w_offset, const float* __restrict__ b_offset,
                     const float* __restrict__ w_dcn, float* __restrict__ ws) {
    int tid = blockIdx.x * 256 + threadIdx.x;
    if (tid < 147456) {
        int o = tid & 63;
        int k = (tid >> 6) % 9;
        int c = (tid / 576) & 63;
        int g = tid / 36864;
        ws[WTOFF + tid] = w_dcn[((g * 64 + o) * 64 + c) * 9 + k];
    }
    if (tid < 62208) {
        int j = tid % 27;
        int r = tid / 27;
        int k = r % 9;
        int gc = r / 9;
        int c = gc & 63;
        int g = gc >> 6;
        int o = off_chan(g, j);
        float s = 0.f;
#pragma unroll
        for (int ss = 0; ss < 4; ++ss)
            s += w_offset[(o * 256 + ss * 64 + c) * 9 + k];
        ws[WEFF2 + tid] = s;
    }
    if (tid < 108) {
        int g = tid / 27, j = tid % 27;
        ws[BIAS2 + tid] = b_offset[off_chan(g, j)];
    }
    if (tid < 128) ws[STATS + tid] = 0.f;
}

// x [b][c][px] f32 -> xT [b][px][c] bf16.  grid 512 (b*256 + tile of 64 px)
__global__ __launch_bounds__(256) void transpose_x(const float* __restrict__ x,
                                                   ushort_t* __restrict__ xT) {
    int b = blockIdx.x >> 8;
    int px0 = (blockIdx.x & 255) << 6;
    __shared__ float lds[64][65];
    int t = threadIdx.x;
    int lx = t & 63;
    int row = t >> 6;
    const float* xb = x + (size_t)b * CH * HW;
#pragma unroll
    for (int i = 0; i < 16; ++i) {
        int c = i * 4 + row;
        lds[c][lx] = xb[(size_t)c * HW + px0 + lx];
    }
    __syncthreads();
    ushort_t* dst = xT + ((size_t)b * HW + px0) * 64;
#pragma unroll
    for (int i = 0; i < 16; ++i) {
        int p = i * 4 + row;
        dst[(size_t)p * 64 + lx] = f2bf(lds[lx][p]);
    }
}

// offset conv, j-chunked by template.  flat grid 512.  XCD owns (b, row-quarter).
template <int JBASE, int JN>
__global__ __launch_bounds__(256, 2) void conv_off(const float* __restrict__ x,
                                                   float* __restrict__ ws) {
    int blk = blockIdx.x;
    int xcd = blk & 7;
    int b = xcd >> 2;
    int quad = xcd & 3;
    int unit = blk >> 3;
    int tl = unit & 15;
    int g = unit >> 4;
    int th = quad * 2 + (tl >> 3);
    int tw = tl & 7;
    int t = threadIdx.x;
    int h = th * 16 + (t >> 4);
    int w = tw * 16 + (t & 15);
    const float* xb = x + (size_t)b * CH * HW;

    float oacc[JN];
    const float* bp = ws + BIAS2 + g * 27 + JBASE;
#pragma unroll
    for (int j = 0; j < JN; ++j) oacc[j] = bp[j];

    int offs[9];
    float vmask[9];
#pragma unroll
    for (int k = 0; k < 9; ++k) {
        int yy = h + k / 3 - 1, xx = w + k % 3 - 1;
        bool v = (yy >= 0) && (yy < HH) && (xx >= 0) && (xx < WW);
        vmask[k] = v ? 1.f : 0.f;
        offs[k] = min(max(yy, 0), HH - 1) * WW + min(max(xx, 0), WW - 1);
    }

    const float* wp0 = ws + WEFF2 + (g * 64) * 243 + JBASE;

    float xra[2][9], xrb[2][9];
#define CLOAD(dst, c0_)                                            \
    {                                                              \
        _Pragma("unroll") for (int cc = 0; cc < 2; ++cc) {         \
            const float* xp = xb + ((c0_) + cc) * HW;              \
            _Pragma("unroll") for (int k = 0; k < 9; ++k)          \
                dst[cc][k] = xp[offs[k]];                          \
        }                                                          \
    }
#define CFMA(src, c0_)                                             \
    {                                                              \
        _Pragma("unroll") for (int cc = 0; cc < 2; ++cc) {         \
            const float* wp = wp0 + ((c0_) + cc) * 243;            \
            _Pragma("unroll") for (int k = 0; k < 9; ++k) {        \
                float xv = src[cc][k] * vmask[k];                  \
                _Pragma("unroll") for (int j = 0; j < JN; ++j)     \
                    oacc[j] = fmaf(xv, wp[k * 27 + j], oacc[j]);   \
            }                                                      \
        }                                                          \
    }
    CLOAD(xra, 0);
#pragma unroll
    for (int c0 = 0; c0 < CH; c0 += 4) {
        CLOAD(xrb, c0 + 2);
        CFMA(xra, c0);
        if (c0 + 4 < CH) CLOAD(xra, c0 + 4);
        CFMA(xrb, c0 + 2);
    }
#undef CLOAD
#undef CFMA

    ushort_t* op = (ushort_t*)(ws + OACC)
                 + (size_t)((b * 4 + g) * 27 + JBASE) * HW + h * WW + w;
#pragma unroll
    for (int j = 0; j < JN; ++j) op[(size_t)j * HW] = f2bf(oacc[j]);
}

// deformable conv, o-chunked (32/block), channel-last bf16 gathers.
// flat grid 1024.  xcd = blk&7 -> (b, quad); unit = blk>>3: tl, go=(g,ohalf)
__global__ __launch_bounds__(256, 2) void dcn(const float* __restrict__ ws_f,
                                              const ushort_t* __restrict__ xT,
                                              const ushort_t* __restrict__ oaccb,
                                              float* __restrict__ out,
                                              float* __restrict__ stats) {
    int blk = blockIdx.x;
    int xcd = blk & 7;
    int b = xcd >> 2;
    int quad = xcd & 3;
    int unit = blk >> 3;
    int tl = unit & 15;
    int go = unit >> 4;
    int g = go & 3;
    int obase = (go >> 2) * 32;
    int th = quad * 2 + (tl >> 3);
    int tw = tl & 7;
    int t = threadIdx.x;
    int h = th * 16 + (t >> 4);
    int w = tw * 16 + (t & 15);
    int px = h * WW + w;
    const ushort_t* xTb = xT + (size_t)b * HW * 64;
    const ushort_t* ob_in = oaccb + (size_t)(b * 4 + g) * 27 * HW + px;

    float acc[32];
#pragma unroll
    for (int o = 0; o < 32; ++o) acc[o] = 0.f;

    const float* wg = ws_f + WTOFF + g * 36864 + obase;

    for (int k = 0; k < 9; ++k) {
        float dy = bfu(ob_in[(size_t)(2 * k) * HW]);
        float dx = bfu(ob_in[(size_t)(2 * k + 1) * HW]);
        float mk = 1.f / (1.f + expf(-bfu(ob_in[(size_t)(18 + k) * HW])));

        float py = (float)h + (float)(k / 3 - 1) + dy;
        float qx = (float)w + (float)(k % 3 - 1) + dx;
        float y0f = floorf(py), x0f = floorf(qx);
        float ly = py - y0f, lx = qx - x0f;
        int y0 = (int)y0f, x0 = (int)x0f;
        int y1 = y0 + 1, x1 = x0 + 1;

        bool vy0 = (y0 >= 0) && (y0 < HH), vy1 = (y1 >= 0) && (y1 < HH);
        bool vx0 = (x0 >= 0) && (x0 < WW), vx1 = (x1 >= 0) && (x1 < WW);
        int yc0 = min(max(y0, 0), HH - 1), yc1 = min(max(y1, 0), HH - 1);
        int xc0 = min(max(x0, 0), WW - 1), xc1 = min(max(x1, 0), WW - 1);
        int i00 = yc0 * WW + xc0, i01 = yc0 * WW + xc1;
        int i10 = yc1 * WW + xc0, i11 = yc1 * WW + xc1;

        float w00 = (1.f - ly) * (1.f - lx) * mk * ((vy0 && vx0) ? 1.f : 0.f);
        float w01 = (1.f - ly) * lx * mk * ((vy0 && vx1) ? 1.f : 0.f);
        float w10 = ly * (1.f - lx) * mk * ((vy1 && vx0) ? 1.f : 0.f);
        float w11 = ly * lx * mk * ((vy1 && vx1) ? 1.f : 0.f);

        // channel-last: each corner's 64 channels are 128 contiguous bytes
        const uint4* p00 = (const uint4*)(xTb + (size_t)i00 * 64);
        const uint4* p01 = (const uint4*)(xTb + (size_t)i01 * 64);
        const uint4* p10 = (const uint4*)(xTb + (size_t)i10 * 64);
        const uint4* p11 = (const uint4*)(xTb + (size_t)i11 * 64);
        const float* wk = wg + k * 64;

#define DOCH(U00, U01, U10, U11, CB)                                        \
    {                                                                       \
        float a00 = bflo(U00), a01 = bflo(U01), a10 = bflo(U10),            \
              a11 = bflo(U11);                                              \
        float col = w00 * a00 + w01 * a01 + w10 * a10 + w11 * a11;          \
        const float* wp = wk + (CB)*576;                                    \
        _Pragma("unroll") for (int o = 0; o < 32; ++o)                      \
            acc[o] = fmaf(col, wp[o], acc[o]);                              \
        a00 = bfhi(U00); a01 = bfhi(U01); a10 = bfhi(U10); a11 = bfhi(U11); \
        col = w00 * a00 + w01 * a01 + w10 * a10 + w11 * a11;                \
        wp = wk + ((CB) + 1) * 576;                                         \
        _Pragma("unroll") for (int o = 0; o < 32; ++o)                      \
            acc[o] = fmaf(col, wp[o], acc[o]);                              \
    }
#define LOADQ(D, CG) { D[0] = p00[CG]; D[1] = p01[CG]; D[2] = p10[CG]; D[3] = p11[CG]; }
#define FMAQ(S, C0)                                  \
    DOCH(S[0].x, S[1].x, S[2].x, S[3].x, (C0) + 0);  \
    DOCH(S[0].y, S[1].y, S[2].y, S[3].y, (C0) + 2);  \
    DOCH(S[0].z, S[1].z, S[2].z, S[3].z, (C0) + 4);  \
    DOCH(S[0].w, S[1].w, S[2].w, S[3].w, (C0) + 6);

        uint4 xa[4], xb2[4];
        LOADQ(xa, 0);
#pragma unroll
        for (int cg = 0; cg < 8; cg += 2) {
            LOADQ(xb2, cg + 1);
            FMAQ(xa, cg * 8);
            if (cg + 2 < 8) LOADQ(xa, cg + 2);
            FMAQ(xb2, (cg + 1) * 8);
        }
#undef DOCH
#undef LOADQ
#undef FMAQ
    }

    int h2 = h * 2 + (g >> 1), w2 = w * 2 + (g & 1);
    float* op = out + (size_t)b * 64 * 65536 + (size_t)obase * 65536
              + (size_t)h2 * 256 + w2;
#pragma unroll
    for (int o = 0; o < 32; ++o)
        op[(size_t)o * 65536] = acc[o];

#pragma unroll
    for (int o = 0; o < 32; ++o) {
        float v = acc[o];
        float v2 = v * v;
#pragma unroll
        for (int m = 32; m >= 1; m >>= 1) {
            v += __shfl_xor(v, m);
            v2 += __shfl_xor(v2, m);
        }
        if ((t & 63) == 0) {
            atomicAdd(stats + obase + o, v);
            atomicAdd(stats + 64 + obase + o, v2);
        }
    }
}

__global__ void finalize(const float* __restrict__ stats,
                         const float* __restrict__ gamma,
                         const float* __restrict__ beta,
                         float* __restrict__ ab) {
    int t = threadIdx.x;
    if (t < 64) {
        float mean = stats[t] / NVALS;
        float var = stats[64 + t] / NVALS - mean * mean;
        var = fmaxf(var, 0.f);
        float a = gamma[t] * rsqrtf(var + 1e-5f);
        ab[t] = a;
        ab[64 + t] = beta[t] - mean * a;
    }
}

__global__ void norm_relu(float* __restrict__ out, const float* __restrict__ ab) {
    size_t tid = (size_t)blockIdx.x * 256 + threadIdx.x;
    size_t base = tid * 4;
    int o = (int)((base >> 16) & 63);
    float a = ab[o], bb = ab[64 + o];
    float4* p = (float4*)(out + base);
    float4 v = *p;
    v.x = fmaxf(fmaf(v.x, a, bb), 0.f);
    v.y = fmaxf(fmaf(v.y, a, bb), 0.f);
    v.z = fmaxf(fmaf(v.z, a, bb), 0.f);
    v.w = fmaxf(fmaf(v.w, a, bb), 0.f);
    *p = v;
}

extern "C" void kernel_launch(void* const* d_in, const int* in_sizes, int n_in,
                              void* d_out, int out_size, void* d_ws, size_t ws_size,
                              hipStream_t stream) {
    const float* x        = (const float*)d_in[0];
    const float* w_offset = (const float*)d_in[1];
    const float* b_offset = (const float*)d_in[2];
    const float* w_dcn    = (const float*)d_in[3];
    const float* gamma    = (const float*)d_in[4];
    const float* beta     = (const float*)d_in[5];
    float* out            = (float*)d_out;
    float* ws = (float*)d_ws;

    prep<<<576, 256, 0, stream>>>(w_offset, b_offset, w_dcn, ws);
    transpose_x<<<512, 256, 0, stream>>>(x, (ushort_t*)(ws + XT));
    conv_off<0, 14><<<512, 256, 0, stream>>>(x, ws);
    conv_off<14, 13><<<512, 256, 0, stream>>>(x, ws);
    dcn<<<1024, 256, 0, stream>>>(ws, (ushort_t*)(ws + XT), (ushort_t*)(ws + OACC),
                                  out, ws + STATS);
    finalize<<<1, 64, 0, stream>>>(ws + STATS, gamma, beta, ws + STATS + 128);
    norm_relu<<<8192, 256, 0, stream>>>(out, ws + STATS + 128);
}

// Round 10
// 574.732 us; speedup vs baseline: 2.7093x; 2.5473x over previous
//
#include <hip/hip_runtime.h>
#include <hip/hip_bf16.h>
#include <math.h>

#define CH 64
#define HH 128
#define WW 128
#define HW 16384
#define NVALS 131072.f

// ws layout (float offsets):
//  WEFF2 62208 f | BIAS2 108 f | WTOFF 147456 f | STATS 256 f
//  OACC: ushort region, 3538944 bf16 (offset-conv out, [b][g][j][px])
//  XT:   ushort region, 2097152 bf16 (x transposed, [b][px][c])
#define WEFF2 0
#define BIAS2 62208
#define WTOFF 62464
#define STATS 209920
#define OACC  210176
#define XT    1979648

typedef unsigned short ushort_t;
typedef unsigned int uint_t;

__device__ __forceinline__ float bflo(uint_t u) { return __uint_as_float(u << 16); }
__device__ __forceinline__ float bfhi(uint_t u) { return __uint_as_float(u & 0xFFFF0000u); }
__device__ __forceinline__ float bfu(ushort_t s) { return __uint_as_float(((uint_t)s) << 16); }
__device__ __forceinline__ ushort_t f2bf(float f) {
    __hip_bfloat16 h = __float2bfloat16(f);
    return *(ushort_t*)&h;
}

__device__ __forceinline__ int off_chan(int g, int j) {
    return (j < 18) ? (g * 18 + j) : (72 + g * 9 + (j - 18));
}

__global__ void prep(const float* __restrict__ w_offset, const float* __restrict__ b_offset,
                     const float* __restrict__ w_dcn, float* __restrict__ ws) {
    int tid = blockIdx.x * 256 + threadIdx.x;
    if (tid < 147456) {
        int o = tid & 63;
        int k = (tid >> 6) % 9;
        int c = (tid / 576) & 63;
        int g = tid / 36864;
        ws[WTOFF + tid] = w_dcn[((g * 64 + o) * 64 + c) * 9 + k];
    }
    if (tid < 62208) {
        int j = tid % 27;
        int r = tid / 27;
        int k = r % 9;
        int gc = r / 9;
        int c = gc & 63;
        int g = gc >> 6;
        int o = off_chan(g, j);
        float s = 0.f;
#pragma unroll
        for (int ss = 0; ss < 4; ++ss)
            s += w_offset[(o * 256 + ss * 64 + c) * 9 + k];
        ws[WEFF2 + tid] = s;
    }
    if (tid < 108) {
        int g = tid / 27, j = tid % 27;
        ws[BIAS2 + tid] = b_offset[off_chan(g, j)];
    }
    if (tid < 128) ws[STATS + tid] = 0.f;
}

// x [b][c][px] f32 -> xT [b][px][c] bf16.  grid 512 (b*256 + tile of 64 px)
__global__ __launch_bounds__(256) void transpose_x(const float* __restrict__ x,
                                                   ushort_t* __restrict__ xT) {
    int b = blockIdx.x >> 8;
    int px0 = (blockIdx.x & 255) << 6;
    __shared__ float lds[64][65];
    int t = threadIdx.x;
    int lx = t & 63;
    int row = t >> 6;
    const float* xb = x + (size_t)b * CH * HW;
#pragma unroll
    for (int i = 0; i < 16; ++i) {
        int c = i * 4 + row;
        lds[c][lx] = xb[(size_t)c * HW + px0 + lx];
    }
    __syncthreads();
    ushort_t* dst = xT + ((size_t)b * HW + px0) * 64;
#pragma unroll
    for (int i = 0; i < 16; ++i) {
        int p = i * 4 + row;
        dst[(size_t)p * 64 + lx] = f2bf(lds[lx][p]);
    }
}

// offset conv, j-chunked by template.  flat grid 512.  XCD owns (b, row-quarter).
template <int JBASE, int JN>
__global__ __launch_bounds__(256, 2) void conv_off(const float* __restrict__ x,
                                                   float* __restrict__ ws) {
    int blk = blockIdx.x;
    int xcd = blk & 7;
    int b = xcd >> 2;
    int quad = xcd & 3;
    int unit = blk >> 3;
    int tl = unit & 15;
    int g = unit >> 4;
    int th = quad * 2 + (tl >> 3);
    int tw = tl & 7;
    int t = threadIdx.x;
    int h = th * 16 + (t >> 4);
    int w = tw * 16 + (t & 15);
    const float* xb = x + (size_t)b * CH * HW;

    float oacc[JN];
    const float* bp = ws + BIAS2 + g * 27 + JBASE;
#pragma unroll
    for (int j = 0; j < JN; ++j) oacc[j] = bp[j];

    int offs[9];
    float vmask[9];
#pragma unroll
    for (int k = 0; k < 9; ++k) {
        int yy = h + k / 3 - 1, xx = w + k % 3 - 1;
        bool v = (yy >= 0) && (yy < HH) && (xx >= 0) && (xx < WW);
        vmask[k] = v ? 1.f : 0.f;
        offs[k] = min(max(yy, 0), HH - 1) * WW + min(max(xx, 0), WW - 1);
    }

    const float* wp0 = ws + WEFF2 + (g * 64) * 243 + JBASE;

    float xra[2][9], xrb[2][9];
#define CLOAD(dst, c0_)                                            \
    {                                                              \
        _Pragma("unroll") for (int cc = 0; cc < 2; ++cc) {         \
            const float* xp = xb + ((c0_) + cc) * HW;              \
            _Pragma("unroll") for (int k = 0; k < 9; ++k)          \
                dst[cc][k] = xp[offs[k]];                          \
        }                                                          \
    }
#define CFMA(src, c0_)                                             \
    {                                                              \
        _Pragma("unroll") for (int cc = 0; cc < 2; ++cc) {         \
            const float* wp = wp0 + ((c0_) + cc) * 243;            \
            _Pragma("unroll") for (int k = 0; k < 9; ++k) {        \
                float xv = src[cc][k] * vmask[k];                  \
                _Pragma("unroll") for (int j = 0; j < JN; ++j)     \
                    oacc[j] = fmaf(xv, wp[k * 27 + j], oacc[j]);   \
            }                                                      \
        }                                                          \
    }
    CLOAD(xra, 0);
#pragma unroll
    for (int c0 = 0; c0 < CH; c0 += 4) {
        CLOAD(xrb, c0 + 2);
        CFMA(xra, c0);
        if (c0 + 4 < CH) CLOAD(xra, c0 + 4);
        CFMA(xrb, c0 + 2);
    }
#undef CLOAD
#undef CFMA

    ushort_t* op = (ushort_t*)(ws + OACC)
                 + (size_t)((b * 4 + g) * 27 + JBASE) * HW + h * WW + w;
#pragma unroll
    for (int j = 0; j < JN; ++j) op[(size_t)j * HW] = f2bf(oacc[j]);
}

// deformable conv, o-chunked (32/block), channel-last bf16 gathers. NO atomics.
__global__ __launch_bounds__(256, 2) void dcn(const float* __restrict__ ws_f,
                                              const ushort_t* __restrict__ xT,
                                              const ushort_t* __restrict__ oaccb,
                                              float* __restrict__ out) {
    int blk = blockIdx.x;
    int xcd = blk & 7;
    int b = xcd >> 2;
    int quad = xcd & 3;
    int unit = blk >> 3;
    int tl = unit & 15;
    int go = unit >> 4;
    int g = go & 3;
    int obase = (go >> 2) * 32;
    int th = quad * 2 + (tl >> 3);
    int tw = tl & 7;
    int t = threadIdx.x;
    int h = th * 16 + (t >> 4);
    int w = tw * 16 + (t & 15);
    int px = h * WW + w;
    const ushort_t* xTb = xT + (size_t)b * HW * 64;
    const ushort_t* ob_in = oaccb + (size_t)(b * 4 + g) * 27 * HW + px;

    float acc[32];
#pragma unroll
    for (int o = 0; o < 32; ++o) acc[o] = 0.f;

    const float* wg = ws_f + WTOFF + g * 36864 + obase;

    for (int k = 0; k < 9; ++k) {
        float dy = bfu(ob_in[(size_t)(2 * k) * HW]);
        float dx = bfu(ob_in[(size_t)(2 * k + 1) * HW]);
        float mk = 1.f / (1.f + expf(-bfu(ob_in[(size_t)(18 + k) * HW])));

        float py = (float)h + (float)(k / 3 - 1) + dy;
        float qx = (float)w + (float)(k % 3 - 1) + dx;
        float y0f = floorf(py), x0f = floorf(qx);
        float ly = py - y0f, lx = qx - x0f;
        int y0 = (int)y0f, x0 = (int)x0f;
        int y1 = y0 + 1, x1 = x0 + 1;

        bool vy0 = (y0 >= 0) && (y0 < HH), vy1 = (y1 >= 0) && (y1 < HH);
        bool vx0 = (x0 >= 0) && (x0 < WW), vx1 = (x1 >= 0) && (x1 < WW);
        int yc0 = min(max(y0, 0), HH - 1), yc1 = min(max(y1, 0), HH - 1);
        int xc0 = min(max(x0, 0), WW - 1), xc1 = min(max(x1, 0), WW - 1);
        int i00 = yc0 * WW + xc0, i01 = yc0 * WW + xc1;
        int i10 = yc1 * WW + xc0, i11 = yc1 * WW + xc1;

        float w00 = (1.f - ly) * (1.f - lx) * mk * ((vy0 && vx0) ? 1.f : 0.f);
        float w01 = (1.f - ly) * lx * mk * ((vy0 && vx1) ? 1.f : 0.f);
        float w10 = ly * (1.f - lx) * mk * ((vy1 && vx0) ? 1.f : 0.f);
        float w11 = ly * lx * mk * ((vy1 && vx1) ? 1.f : 0.f);

        const uint4* p00 = (const uint4*)(xTb + (size_t)i00 * 64);
        const uint4* p01 = (const uint4*)(xTb + (size_t)i01 * 64);
        const uint4* p10 = (const uint4*)(xTb + (size_t)i10 * 64);
        const uint4* p11 = (const uint4*)(xTb + (size_t)i11 * 64);
        const float* wk = wg + k * 64;

#define DOCH(U00, U01, U10, U11, CB)                                        \
    {                                                                       \
        float a00 = bflo(U00), a01 = bflo(U01), a10 = bflo(U10),            \
              a11 = bflo(U11);                                              \
        float col = w00 * a00 + w01 * a01 + w10 * a10 + w11 * a11;          \
        const float* wp = wk + (CB)*576;                                    \
        _Pragma("unroll") for (int o = 0; o < 32; ++o)                      \
            acc[o] = fmaf(col, wp[o], acc[o]);                              \
        a00 = bfhi(U00); a01 = bfhi(U01); a10 = bfhi(U10); a11 = bfhi(U11); \
        col = w00 * a00 + w01 * a01 + w10 * a10 + w11 * a11;                \
        wp = wk + ((CB) + 1) * 576;                                         \
        _Pragma("unroll") for (int o = 0; o < 32; ++o)                      \
            acc[o] = fmaf(col, wp[o], acc[o]);                              \
    }
#define LOADQ(D, CG) { D[0] = p00[CG]; D[1] = p01[CG]; D[2] = p10[CG]; D[3] = p11[CG]; }
#define FMAQ(S, C0)                                  \
    DOCH(S[0].x, S[1].x, S[2].x, S[3].x, (C0) + 0);  \
    DOCH(S[0].y, S[1].y, S[2].y, S[3].y, (C0) + 2);  \
    DOCH(S[0].z, S[1].z, S[2].z, S[3].z, (C0) + 4);  \
    DOCH(S[0].w, S[1].w, S[2].w, S[3].w, (C0) + 6);

        uint4 xa[4], xb2[4];
        LOADQ(xa, 0);
#pragma unroll
        for (int cg = 0; cg < 8; cg += 2) {
            LOADQ(xb2, cg + 1);
            FMAQ(xa, cg * 8);
            if (cg + 2 < 8) LOADQ(xa, cg + 2);
            FMAQ(xb2, (cg + 1) * 8);
        }
#undef DOCH
#undef LOADQ
#undef FMAQ
    }

    int h2 = h * 2 + (g >> 1), w2 = w * 2 + (g & 1);
    float* op = out + (size_t)b * 64 * 65536 + (size_t)obase * 65536
              + (size_t)h2 * 256 + w2;
#pragma unroll
    for (int o = 0; o < 32; ++o)
        op[(size_t)o * 65536] = acc[o];
}

// per-channel sum/sumsq over out (pre-norm).  grid 64 (one block per channel).
__global__ __launch_bounds__(256) void stats_sum(const float* __restrict__ out,
                                                 float* __restrict__ stats) {
    int o = blockIdx.x;
    int t = threadIdx.x;
    float s = 0.f, s2 = 0.f;
#pragma unroll
    for (int b = 0; b < 2; ++b) {
        const float* p = out + (size_t)b * 64 * 65536 + (size_t)o * 65536;
        for (int i = t * 4; i < 65536; i += 1024) {
            float4 v = *(const float4*)(p + i);
            s += v.x + v.y + v.z + v.w;
            s2 += v.x * v.x + v.y * v.y + v.z * v.z + v.w * v.w;
        }
    }
    __shared__ float red[512];
    red[t] = s;
    red[256 + t] = s2;
    __syncthreads();
#pragma unroll
    for (int m = 128; m >= 1; m >>= 1) {
        if (t < m) {
            red[t] += red[t + m];
            red[256 + t] += red[256 + t + m];
        }
        __syncthreads();
    }
    if (t == 0) {
        stats[o] = red[0];
        stats[64 + o] = red[256];
    }
}

__global__ void finalize(const float* __restrict__ stats,
                         const float* __restrict__ gamma,
                         const float* __restrict__ beta,
                         float* __restrict__ ab) {
    int t = threadIdx.x;
    if (t < 64) {
        float mean = stats[t] / NVALS;
        float var = stats[64 + t] / NVALS - mean * mean;
        var = fmaxf(var, 0.f);
        float a = gamma[t] * rsqrtf(var + 1e-5f);
        ab[t] = a;
        ab[64 + t] = beta[t] - mean * a;
    }
}

__global__ void norm_relu(float* __restrict__ out, const float* __restrict__ ab) {
    size_t tid = (size_t)blockIdx.x * 256 + threadIdx.x;
    size_t base = tid * 4;
    int o = (int)((base >> 16) & 63);
    float a = ab[o], bb = ab[64 + o];
    float4* p = (float4*)(out + base);
    float4 v = *p;
    v.x = fmaxf(fmaf(v.x, a, bb), 0.f);
    v.y = fmaxf(fmaf(v.y, a, bb), 0.f);
    v.z = fmaxf(fmaf(v.z, a, bb), 0.f);
    v.w = fmaxf(fmaf(v.w, a, bb), 0.f);
    *p = v;
}

extern "C" void kernel_launch(void* const* d_in, const int* in_sizes, int n_in,
                              void* d_out, int out_size, void* d_ws, size_t ws_size,
                              hipStream_t stream) {
    const float* x        = (const float*)d_in[0];
    const float* w_offset = (const float*)d_in[1];
    const float* b_offset = (const float*)d_in[2];
    const float* w_dcn    = (const float*)d_in[3];
    const float* gamma    = (const float*)d_in[4];
    const float* beta     = (const float*)d_in[5];
    float* out            = (float*)d_out;
    float* ws = (float*)d_ws;

    prep<<<576, 256, 0, stream>>>(w_offset, b_offset, w_dcn, ws);
    transpose_x<<<512, 256, 0, stream>>>(x, (ushort_t*)(ws + XT));
    conv_off<0, 14><<<512, 256, 0, stream>>>(x, ws);
    conv_off<14, 13><<<512, 256, 0, stream>>>(x, ws);
    dcn<<<1024, 256, 0, stream>>>(ws, (ushort_t*)(ws + XT), (ushort_t*)(ws + OACC), out);
    stats_sum<<<64, 256, 0, stream>>>(out, ws + STATS);
    finalize<<<1, 64, 0, stream>>>(ws + STATS, gamma, beta, ws + STATS + 128);
    norm_relu<<<8192, 256, 0, stream>>>(out, ws + STATS + 128);
}